// Round 4
// baseline (878.378 us; speedup 1.0000x reference)
//
#include <hip/hip_runtime.h>

#define NTOK  384
#define SPANS 73920          // 384*385/2
#define MTILES 584           // 73*8 so grid=584*8 maps cleanly onto 8 XCDs
#define MPAD  (MTILES * 128) // 74752
#define HD    1024
#define BK    32
#define KTS   (HD / BK)      // 32

typedef unsigned short u16;
typedef __attribute__((ext_vector_type(8))) short short8;
typedef __attribute__((ext_vector_type(4))) float floatx4;

// gfx9 s_waitcnt immediate: vmcnt[3:0]|[15:14], expcnt[6:4], lgkmcnt[11:8]
#define VMCNT_IMM(N) (((N) & 0xF) | (((N) >> 4) << 14) | (0x7 << 4) | (0xF << 8))

__device__ __forceinline__ u16 f2bu(float x) {
  union { float f; unsigned u; } un; un.f = x;
  unsigned r = un.u + 0x7fffu + ((un.u >> 16) & 1u);   // RNE
  return (u16)(r >> 16);
}

__device__ __forceinline__ void gld_lds16(const void* g, void* l) {
  __builtin_amdgcn_global_load_lds(
      (const __attribute__((address_space(1))) void*)g,
      (__attribute__((address_space(3))) void*)l, 16, 0, 0);
}

// ---- prep: gather token embeddings as bf16 [384][1024] (A of the Y-GEMM) ----
__global__ void emb_gather(const int* __restrict__ sent, const int* __restrict__ pos,
                           const float* __restrict__ Wwrd, const float* __restrict__ Wpos,
                           u16* __restrict__ embB) {
  int t = blockIdx.x;           // token
  int c = threadIdx.x;          // 0..255
  int pt = pos[t], st = sent[t];
  #pragma unroll
  for (int u = 0; u < 4; ++u) {
    int col = u * 256 + c;
    float v = (col < 512) ? Wpos[(size_t)pt * 512 + col]
                          : Wwrd[(size_t)st * 512 + (col - 512)];
    embB[(size_t)t * HD + col] = f2bu(v);
  }
}

// ---- prep: span (i, end, 1/len) + scores init (folded) ----
__global__ void prep_spans(int* __restrict__ spI, int* __restrict__ spE, float* __restrict__ spInv,
                           float* __restrict__ scores, const float* __restrict__ bs2) {
  int rf = blockIdx.x * 256 + threadIdx.x;
  if (rf >= MPAD) return;
  int s = rf < SPANS ? rf : SPANS - 1;
  const int n = NTOK;
  double tn = 2.0 * n + 1.0;
  int i = (int)((tn - sqrt(tn * tn - 8.0 * (double)s)) * 0.5);
  if (i < 0) i = 0;
  if (i > n - 1) i = n - 1;
  #define OFF(ii) (((ii) * (2 * n - (ii) + 1)) / 2)
  while (i + 1 <= n - 1 && OFF(i + 1) <= s) ++i;
  while (i > 0 && OFF(i) > s) --i;
  int j = i + (s - OFF(i));
  #undef OFF
  spI[rf] = i;
  spE[rf] = j + 1;
  spInv[rf] = 1.0f / (float)(j + 1 - i);
  if (rf < SPANS) scores[rf] = bs2[0];
}

// ---- prep: transpose+cast the three 1024x1024 weight blocks to bf16 B^T [N][K] ----
__global__ void prep_castT(const float* __restrict__ Wd1, const float* __restrict__ Wd2,
                           const float* __restrict__ Ws1,
                           u16* __restrict__ o1, u16* __restrict__ o2, u16* __restrict__ o3) {
  int b = blockIdx.x;           // 3*1024 blocks
  int w = b >> 10, rem = b & 1023;
  int tk = rem >> 5, tn = rem & 31;
  const float* src = (w == 0) ? Wd1 : ((w == 1) ? Wd2 : Ws1);
  u16* dst = (w == 0) ? o1 : ((w == 1) ? o2 : o3);
  __shared__ u16 tile[32][33];
  int x = threadIdx.x & 31, y = threadIdx.x >> 5;   // y in 0..7
  int k0 = tk * 32, n0 = tn * 32;
  for (int yy = 0; yy < 32; yy += 8)
    tile[y + yy][x] = f2bu(src[(size_t)(k0 + y + yy) * HD + n0 + x]);
  __syncthreads();
  for (int yy = 0; yy < 32; yy += 8)
    dst[(size_t)(n0 + y + yy) * HD + k0 + x] = tile[x][y + yy];
}

// ---- prep: S0/S1/S2 = column sums of W_s1's feat rows (len/start/end, 16 each), exact fp32 ----
__global__ void prep_svec(const float* __restrict__ Ws1,
                          float* __restrict__ S0, float* __restrict__ S1v, float* __restrict__ S2v) {
  int c = blockIdx.x * 256 + threadIdx.x;
  if (c >= HD) return;
  float a = 0.f, b = 0.f, d = 0.f;
  for (int r = 0; r < 16; ++r) {
    a += Ws1[(size_t)(1024 + r) * HD + c];
    b += Ws1[(size_t)(1040 + r) * HD + c];
    d += Ws1[(size_t)(1056 + r) * HD + c];
  }
  S0[c] = a; S1v[c] = b; S2v[c] = d;
}

// ---- Qp = [0; cumsum(Y, rows)] fp32, per-column parallel scan ----
__global__ void yscan(const float* __restrict__ Y, float* __restrict__ Qp) {
  __shared__ float buf[NTOK];
  int c = blockIdx.x;           // 0..1023
  int t = threadIdx.x;          // 0..383
  buf[t] = Y[(size_t)t * HD + c];
  __syncthreads();
  #pragma unroll
  for (int off = 1; off < NTOK; off <<= 1) {
    float add = (t >= off) ? buf[t - off] : 0.f;
    __syncthreads();
    buf[t] += add;
    __syncthreads();
  }
  if (t == 0) Qp[c] = 0.f;
  Qp[(size_t)(t + 1) * HD + c] = buf[t];
}

// ---- expand: h1[s] = relu((Qp[e]-Qp[i])*inv + b1) -> bf16 [MPAD][1024] ----
// Replaces the 1.6e11-FLOP GEMM1: matmul is linear in the span mean, so
// mean@W1 = (prefix(Y)[e]-prefix(Y)[i])*inv with Y = emb@W1 (tiny GEMM).
__global__ void expand(const float* __restrict__ Qp, const int* __restrict__ spI,
                       const int* __restrict__ spE, const float* __restrict__ spInv,
                       const float* __restrict__ b1, u16* __restrict__ out) {
  int gid = blockIdx.x * 256 + threadIdx.x;   // MPAD*128 threads
  int row = gid >> 7;
  int c0 = (gid & 127) << 3;
  int i = spI[row], e = spE[row];
  float inv = spInv[row];
  const float* pe = Qp + (size_t)e * HD + c0;
  const float* pi = Qp + (size_t)i * HD + c0;
  const float* bb = b1 + c0;
  u16 tmp[8];
  #pragma unroll
  for (int u = 0; u < 8; ++u) {
    float v = (pe[u] - pi[u]) * inv + bb[u];
    v = v > 0.f ? v : 0.f;
    tmp[u] = f2bu(v);
  }
  *(uint4*)(out + (size_t)row * HD + c0) = *(const uint4*)tmp;
}

// ---- GEMM: C[M,1024] = A[M,1024] @ B^T[1024,1024]^T (+ bias, relu)
// 128x128 tile, 4 waves of 64x64, 16x16x32 MFMA, BK=32.
// Round-4 change: B operand is DIRECT global->register (no LDS). B is 2 MB,
// L1/L2-resident; lane l loads Bt[n0+wn*64+ni*16+r][kt*32+q*8..+7] as one
// dwordx4 — bit-identical to what the old LDS swizzle path delivered.
// A stays on the proven gld_lds HBM-streaming path (0-conflict stripe layout).
// LDS traffic per block-K-step: 48 KB -> 24 KB (stage 8 + read 16), below the
// 256-cyc MFMA demand -> LDS leaves the critical path.
// B loads double-buffered in registers (bfr0/bfr1, static indexing), issued
// together with the A-stage ops and pinned by sched_barrier(0) so the counted
// vmcnt(6) (= kt+1's 2 stage + 4 B loads in flight) stays valid.
// EPI==0: relu+bias, store bf16 C.
// EPI==1: + feats affine, relu, dot W_s2, atomicAdd scores.
// EPI==2: plain fp32 store (no bias/relu), simple block mapping (small Y-GEMM).
template <int EPI>
__global__ __launch_bounds__(256, 3) void gemm_bt(
    const u16* __restrict__ A, const u16* __restrict__ Bt,
    const float* __restrict__ bias, u16* __restrict__ C, float* __restrict__ Cf,
    const int* __restrict__ spI, const int* __restrict__ spE,
    const float* __restrict__ S0, const float* __restrict__ S1v, const float* __restrict__ S2v,
    const float* __restrict__ Ws2, float* __restrict__ scores) {
  __shared__ u16 As[2][128 * BK];   // 8 KB per buffer; [stripe(64)][128B]
  int bx = blockIdx.x;
  int mt, nt;
  if (EPI == 2) {
    nt = bx & 7; mt = bx >> 3;      // tiny GEMM: plain mapping
  } else {
    int xcd = bx & 7, k = bx >> 3;
    nt = k & 7;
    mt = xcd + 8 * (k >> 3);        // mt%8 == xcd; blocks per XCD share mt (A L2 reuse)
  }
  int m0 = mt * 128, n0 = nt * 128;
  int t = threadIdx.x, lane = t & 63, wid = t >> 6;
  int wm = wid >> 1, wn = wid & 1;
  int q = lane >> 4, r = lane & 15;

  floatx4 acc[4][4] = {};

  // ---- A staging geometry (stripe s holds rows 2s,2s+1; sub=(row&1)*4+koct at
  // octet sub^(s&7); one DMA op = 16 rows x 64B, swizzle invariant under +64 rows) ----
  int dsub = (lane & 7) ^ ((lane >> 3) & 7);
  int row0 = wid * 16 + 2 * (lane >> 3) + (dsub >> 2);
  int voff = row0 * HD + (dsub & 3) * 8;          // u16 elems; kt-invariant
  const u16* gA0 = A + (size_t)m0 * HD;
  int ldsOff0 = wid * 512;                        // u16; wave-uniform dests
  int ldsOff1 = 2048 + wid * 512;                 // +64 rows = +32 stripes

  auto stage = [&](int kt, int b) {
    const u16* pa = gA0 + voff + kt * BK;
    gld_lds16(pa,                   &As[b][ldsOff0]);
    gld_lds16(pa + (size_t)64 * HD, &As[b][ldsOff1]);
  };

  // ---- B fragment direct-load base: lane l covers Bt row (col) wn*64+ni*16+r,
  // k-slice q*8..q*8+7 within the kt*32 K-step ----
  const u16* gBf = Bt + ((size_t)(n0 + wn * 64 + r)) * HD + q * 8;
  auto loadB = [&](int kt, short8 (&bf)[4]) {
    #pragma unroll
    for (int ni = 0; ni < 4; ++ni)
      bf[ni] = *(const short8*)(gBf + (size_t)ni * 16 * HD + kt * BK);
  };

  // ---- A fragment read offsets (u16 elements) ----
  int oct = (((r & 1) << 2) + q) ^ ((r >> 1) & 7);
  int aoff[4];
  #pragma unroll
  for (int x = 0; x < 4; ++x)
    aoff[x] = (wm * 32 + x * 8 + (r >> 1)) * 64 + oct * 8;

  auto compute = [&](int b, short8 (&bf)[4]) {
    short8 af[4];
    #pragma unroll
    for (int x = 0; x < 4; ++x) af[x] = *(const short8*)(&As[b][aoff[x]]);
    #pragma unroll
    for (int ni = 0; ni < 4; ++ni)
      #pragma unroll
      for (int mi = 0; mi < 4; ++mi)
        acc[mi][ni] = __builtin_amdgcn_mfma_f32_16x16x32_bf16(af[mi], bf[ni], acc[mi][ni], 0, 0, 0);
  };

  short8 bfr0[4], bfr1[4];
  stage(0, 0);
  loadB(0, bfr0);
  #pragma unroll 1
  for (int kt = 0; kt < KTS; kt += 2) {
    // ---- even step: buf 0, bfr0 ----
    stage(kt + 1, 1);
    loadB(kt + 1, bfr1);
    __builtin_amdgcn_sched_barrier(0);            // pin loads above the counted wait
    __builtin_amdgcn_s_waitcnt(VMCNT_IMM(6));     // kt's 2 stage + 4 B done; kt+1's 6 in flight
    __builtin_amdgcn_s_barrier();
    compute(0, bfr0);
    __builtin_amdgcn_s_barrier();                 // all waves done reading As[0]
    // ---- odd step: buf 1, bfr1 ----
    if (kt + 2 < KTS) {
      stage(kt + 2, 0);
      loadB(kt + 2, bfr0);
      __builtin_amdgcn_sched_barrier(0);
      __builtin_amdgcn_s_waitcnt(VMCNT_IMM(6));
    } else {
      __builtin_amdgcn_sched_barrier(0);
      __builtin_amdgcn_s_waitcnt(VMCNT_IMM(0));
    }
    __builtin_amdgcn_s_barrier();
    compute(1, bfr1);
    __builtin_amdgcn_s_barrier();
  }

  if (EPI == 2) {
    #pragma unroll
    for (int mi = 0; mi < 4; ++mi) {
      int rowb = m0 + wm * 64 + mi * 16 + q * 4;
      #pragma unroll
      for (int ni = 0; ni < 4; ++ni) {
        int col = n0 + wn * 64 + ni * 16 + r;
        #pragma unroll
        for (int e = 0; e < 4; ++e)
          Cf[(size_t)(rowb + e) * HD + col] = acc[mi][ni][e];
      }
    }
  } else if (EPI == 0) {
    #pragma unroll
    for (int mi = 0; mi < 4; ++mi) {
      int rowb = m0 + wm * 64 + mi * 16 + q * 4;
      #pragma unroll
      for (int ni = 0; ni < 4; ++ni) {
        int col = n0 + wn * 64 + ni * 16 + r;
        float bcol = bias[col];
        #pragma unroll
        for (int e = 0; e < 4; ++e) {
          float v = acc[mi][ni][e] + bcol;
          v = v > 0.f ? v : 0.f;
          C[(size_t)(rowb + e) * HD + col] = f2bu(v);
        }
      }
    }
  } else {
    float bcol[4], s0c[4], s1c[4], s2c[4], wsc[4];
    #pragma unroll
    for (int ni = 0; ni < 4; ++ni) {
      int col = n0 + wn * 64 + ni * 16 + r;
      bcol[ni] = bias[col]; s0c[ni] = S0[col]; s1c[ni] = S1v[col];
      s2c[ni] = S2v[col];  wsc[ni] = Ws2[col];
    }
    #pragma unroll
    for (int mi = 0; mi < 4; ++mi) {
      int rowb = m0 + wm * 64 + mi * 16 + q * 4;
      #pragma unroll
      for (int e = 0; e < 4; ++e) {
        int row = rowb + e;
        float fi = (float)spI[row];
        float fe = (float)spE[row];
        float fl = fe - fi;
        float p = 0.f;
        #pragma unroll
        for (int ni = 0; ni < 4; ++ni) {
          float v = acc[mi][ni][e] + bcol[ni] + fl * s0c[ni] + fi * s1c[ni] + fe * s2c[ni];
          v = v > 0.f ? v : 0.f;
          p += v * wsc[ni];
        }
        p += __shfl_xor(p, 1);
        p += __shfl_xor(p, 2);
        p += __shfl_xor(p, 4);
        p += __shfl_xor(p, 8);
        if (r == 0 && row < SPANS) atomicAdd(&scores[row], p);
      }
    }
  }
}

extern "C" void kernel_launch(void* const* d_in, const int* in_sizes, int n_in,
                              void* d_out, int out_size, void* d_ws, size_t ws_size,
                              hipStream_t stream) {
  const int*   sent = (const int*)d_in[0];
  const int*   pos  = (const int*)d_in[1];
  const float* Wwrd = (const float*)d_in[2];
  const float* Wpos = (const float*)d_in[3];
  const float* Wd1  = (const float*)d_in[4];
  const float* bd1  = (const float*)d_in[5];
  const float* Wd2  = (const float*)d_in[6];
  const float* bd2  = (const float*)d_in[7];
  const float* Ws1  = (const float*)d_in[8];
  const float* bs1  = (const float*)d_in[9];
  const float* Ws2  = (const float*)d_in[10];
  const float* bs2  = (const float*)d_in[11];
  float* scores = (float*)d_out;

  char* w = (char*)d_ws;
  size_t o = 0;
  auto alloc = [&](size_t bytes) {
    char* p = w + o;
    o = (o + bytes + 255) & ~(size_t)255;
    return p;
  };
  int*   spI   = (int*)  alloc((size_t)MPAD * 4);
  int*   spE   = (int*)  alloc((size_t)MPAD * 4);
  float* spInv = (float*)alloc((size_t)MPAD * 4);
  float* S0    = (float*)alloc(4096);
  float* S1v   = (float*)alloc(4096);
  float* S2v   = (float*)alloc(4096);
  u16*   embB  = (u16*)  alloc((size_t)NTOK * HD * 2);
  float* Ybuf  = (float*)alloc((size_t)NTOK * HD * 4);
  float* Qp    = (float*)alloc((size_t)(NTOK + 1) * HD * 4);
  u16* Wd1t = (u16*)alloc((size_t)HD * HD * 2);
  u16* Wd2t = (u16*)alloc((size_t)HD * HD * 2);
  u16* Ws1t = (u16*)alloc((size_t)HD * HD * 2);
  u16* bufA = (u16*)alloc((size_t)MPAD * HD * 2);
  u16* bufB = (u16*)alloc((size_t)MPAD * HD * 2);

  emb_gather<<<NTOK, 256, 0, stream>>>(sent, pos, Wwrd, Wpos, embB);
  prep_spans<<<(MPAD + 255) / 256, 256, 0, stream>>>(spI, spE, spInv, scores, bs2);
  prep_castT<<<3 * 1024, 256, 0, stream>>>(Wd1, Wd2, Ws1, Wd1t, Wd2t, Ws1t);
  prep_svec <<<4, 256, 0, stream>>>(Ws1, S0, S1v, S2v);

  // Y = emb @ Wd1  (384x1024x1024, 24 blocks, fp32 out)
  gemm_bt<2><<<(NTOK / 128) * 8, 256, 0, stream>>>(embB, Wd1t, nullptr, nullptr, Ybuf,
                                                   nullptr, nullptr, nullptr, nullptr, nullptr,
                                                   nullptr, nullptr);
  yscan<<<HD, NTOK, 0, stream>>>(Ybuf, Qp);
  expand<<<MPAD / 2, 256, 0, stream>>>(Qp, spI, spE, spInv, bd1, bufA);

  gemm_bt<0><<<MTILES * 8, 256, 0, stream>>>(bufA, Wd2t, bd2, bufB, nullptr,
                                             nullptr, nullptr, nullptr, nullptr, nullptr,
                                             nullptr, nullptr);
  gemm_bt<1><<<MTILES * 8, 256, 0, stream>>>(bufB, Ws1t, bs1, nullptr, nullptr,
                                             spI, spE, S0, S1v, S2v, Ws2, scores);
}

// Round 5
// 646.158 us; speedup vs baseline: 1.3594x; 1.3594x over previous
//
#include <hip/hip_runtime.h>

#define NTOK  384
#define SPANS 73920          // 384*385/2
#define MTILES 584           // 73*8 so grid=584*8 maps cleanly onto 8 XCDs
#define MPAD  (MTILES * 128) // 74752
#define HD    1024
#define BK    32
#define KTS   (HD / BK)      // 32

typedef unsigned short u16;
typedef __attribute__((ext_vector_type(8))) short short8;
typedef __attribute__((ext_vector_type(4))) float floatx4;

// gfx9 s_waitcnt immediate: vmcnt[3:0]|[15:14], expcnt[6:4], lgkmcnt[11:8]
#define VMCNT_IMM(N) (((N) & 0xF) | (((N) >> 4) << 14) | (0x7 << 4) | (0xF << 8))

__device__ __forceinline__ u16 f2bu(float x) {
  union { float f; unsigned u; } un; un.f = x;
  unsigned r = un.u + 0x7fffu + ((un.u >> 16) & 1u);   // RNE
  return (u16)(r >> 16);
}

__device__ __forceinline__ void gld_lds16(const void* g, void* l) {
  __builtin_amdgcn_global_load_lds(
      (const __attribute__((address_space(1))) void*)g,
      (__attribute__((address_space(3))) void*)l, 16, 0, 0);
}

// ---- prep: gather token embeddings as bf16 [384][1024] (A of the Y-GEMM) ----
__global__ void emb_gather(const int* __restrict__ sent, const int* __restrict__ pos,
                           const float* __restrict__ Wwrd, const float* __restrict__ Wpos,
                           u16* __restrict__ embB) {
  int t = blockIdx.x;           // token
  int c = threadIdx.x;          // 0..255
  int pt = pos[t], st = sent[t];
  #pragma unroll
  for (int u = 0; u < 4; ++u) {
    int col = u * 256 + c;
    float v = (col < 512) ? Wpos[(size_t)pt * 512 + col]
                          : Wwrd[(size_t)st * 512 + (col - 512)];
    embB[(size_t)t * HD + col] = f2bu(v);
  }
}

// ---- prep: span (i, end, 1/len) + scores init (folded) ----
__global__ void prep_spans(int* __restrict__ spI, int* __restrict__ spE, float* __restrict__ spInv,
                           float* __restrict__ scores, const float* __restrict__ bs2) {
  int rf = blockIdx.x * 256 + threadIdx.x;
  if (rf >= MPAD) return;
  int s = rf < SPANS ? rf : SPANS - 1;
  const int n = NTOK;
  double tn = 2.0 * n + 1.0;
  int i = (int)((tn - sqrt(tn * tn - 8.0 * (double)s)) * 0.5);
  if (i < 0) i = 0;
  if (i > n - 1) i = n - 1;
  #define OFF(ii) (((ii) * (2 * n - (ii) + 1)) / 2)
  while (i + 1 <= n - 1 && OFF(i + 1) <= s) ++i;
  while (i > 0 && OFF(i) > s) --i;
  int j = i + (s - OFF(i));
  #undef OFF
  spI[rf] = i;
  spE[rf] = j + 1;
  spInv[rf] = 1.0f / (float)(j + 1 - i);
  if (rf < SPANS) scores[rf] = bs2[0];
}

// ---- prep: transpose+cast the three 1024x1024 weight blocks to bf16 B^T [N][K] ----
__global__ void prep_castT(const float* __restrict__ Wd1, const float* __restrict__ Wd2,
                           const float* __restrict__ Ws1,
                           u16* __restrict__ o1, u16* __restrict__ o2, u16* __restrict__ o3) {
  int b = blockIdx.x;           // 3*1024 blocks
  int w = b >> 10, rem = b & 1023;
  int tk = rem >> 5, tn = rem & 31;
  const float* src = (w == 0) ? Wd1 : ((w == 1) ? Wd2 : Ws1);
  u16* dst = (w == 0) ? o1 : ((w == 1) ? o2 : o3);
  __shared__ u16 tile[32][33];
  int x = threadIdx.x & 31, y = threadIdx.x >> 5;   // y in 0..7
  int k0 = tk * 32, n0 = tn * 32;
  for (int yy = 0; yy < 32; yy += 8)
    tile[y + yy][x] = f2bu(src[(size_t)(k0 + y + yy) * HD + n0 + x]);
  __syncthreads();
  for (int yy = 0; yy < 32; yy += 8)
    dst[(size_t)(n0 + y + yy) * HD + k0 + x] = tile[x][y + yy];
}

// ---- prep: S0/S1/S2 = column sums of W_s1's feat rows (len/start/end, 16 each), exact fp32 ----
__global__ void prep_svec(const float* __restrict__ Ws1,
                          float* __restrict__ S0, float* __restrict__ S1v, float* __restrict__ S2v) {
  int c = blockIdx.x * 256 + threadIdx.x;
  if (c >= HD) return;
  float a = 0.f, b = 0.f, d = 0.f;
  for (int r = 0; r < 16; ++r) {
    a += Ws1[(size_t)(1024 + r) * HD + c];
    b += Ws1[(size_t)(1040 + r) * HD + c];
    d += Ws1[(size_t)(1056 + r) * HD + c];
  }
  S0[c] = a; S1v[c] = b; S2v[c] = d;
}

// ---- Qp = [0; cumsum(Y, rows)] fp32, per-column parallel scan ----
__global__ void yscan(const float* __restrict__ Y, float* __restrict__ Qp) {
  __shared__ float buf[NTOK];
  int c = blockIdx.x;           // 0..1023
  int t = threadIdx.x;          // 0..383
  buf[t] = Y[(size_t)t * HD + c];
  __syncthreads();
  #pragma unroll
  for (int off = 1; off < NTOK; off <<= 1) {
    float add = (t >= off) ? buf[t - off] : 0.f;
    __syncthreads();
    buf[t] += add;
    __syncthreads();
  }
  if (t == 0) Qp[c] = 0.f;
  Qp[(size_t)(t + 1) * HD + c] = buf[t];
}

// ---- expand: h1[s] = relu((Qp[e]-Qp[i])*inv + b1) -> bf16 [MPAD][1024] ----
// Replaces the 1.6e11-FLOP GEMM1: matmul is linear in the span mean, so
// mean@W1 = (prefix(Y)[e]-prefix(Y)[i])*inv with Y = emb@W1 (tiny GEMM).
__global__ void expand(const float* __restrict__ Qp, const int* __restrict__ spI,
                       const int* __restrict__ spE, const float* __restrict__ spInv,
                       const float* __restrict__ b1, u16* __restrict__ out) {
  int gid = blockIdx.x * 256 + threadIdx.x;   // MPAD*128 threads
  int row = gid >> 7;
  int c0 = (gid & 127) << 3;
  int i = spI[row], e = spE[row];
  float inv = spInv[row];
  const float* pe = Qp + (size_t)e * HD + c0;
  const float* pi = Qp + (size_t)i * HD + c0;
  const float* bb = b1 + c0;
  u16 tmp[8];
  #pragma unroll
  for (int u = 0; u < 8; ++u) {
    float v = (pe[u] - pi[u]) * inv + bb[u];
    v = v > 0.f ? v : 0.f;
    tmp[u] = f2bu(v);
  }
  *(uint4*)(out + (size_t)row * HD + c0) = *(const uint4*)tmp;
}

// ---- GEMM: C[M,1024] = A[M,1024] @ B^T[1024,1024]^T (+ bias, relu)
// 128x128 tile, 4 waves of 64x64, 16x16x32 MFMA, BK=32,
// 0-conflict stripe layout (2 rows per 128-B stripe).
// Round-5 change: 2-buffer ping-pong (2 barriers/K-step, stage waited 1 iter
// after issue < HBM latency) -> 3-slot LDS ring with ONE barrier per K-step:
//   vmcnt(4)  -- own stage(kt) landed (issued 2 iters ago, ~1400cyc in flight)
//   s_barrier -- => ALL waves' stage(kt) landed AND all finished compute(kt-1)
//   stage(kt+2) into slot (kt-1)%3 -- provably free after the barrier
//   compute(kt)
// LDS 48 KB -> still 3 blocks/CU.
// EPI==0: relu+bias, store bf16 C.
// EPI==1: + feats affine, relu, dot W_s2, atomicAdd scores.
// EPI==2: plain fp32 store (no bias/relu), simple block mapping (small Y-GEMM).
template <int EPI>
__global__ __launch_bounds__(256, 3) void gemm_bt(
    const u16* __restrict__ A, const u16* __restrict__ Bt,
    const float* __restrict__ bias, u16* __restrict__ C, float* __restrict__ Cf,
    const int* __restrict__ spI, const int* __restrict__ spE,
    const float* __restrict__ S0, const float* __restrict__ S1v, const float* __restrict__ S2v,
    const float* __restrict__ Ws2, float* __restrict__ scores) {
  __shared__ u16 As[3][128 * BK];   // 8 KB per slot; [stripe(64)][128B]
  __shared__ u16 Bs[3][128 * BK];
  int bx = blockIdx.x;
  int mt, nt;
  if (EPI == 2) {
    nt = bx & 7; mt = bx >> 3;      // tiny GEMM: plain mapping
  } else {
    int xcd = bx & 7, k = bx >> 3;
    nt = k & 7;
    mt = xcd + 8 * (k >> 3);        // mt%8 == xcd; blocks per XCD share mt (A L2 reuse)
  }
  int m0 = mt * 128, n0 = nt * 128;
  int t = threadIdx.x, lane = t & 63, wid = t >> 6;
  int wm = wid >> 1, wn = wid & 1;
  int q = lane >> 4, r = lane & 15;

  floatx4 acc[4][4] = {};

  // ---- staging geometry (stripe s holds rows 2s,2s+1; sub=(row&1)*4+koct at
  // octet sub^(s&7); one DMA op = 16 rows x 64B, swizzle invariant under +64 rows) ----
  int dsub = (lane & 7) ^ ((lane >> 3) & 7);
  int row0 = wid * 16 + 2 * (lane >> 3) + (dsub >> 2);
  int voff = row0 * HD + (dsub & 3) * 8;          // u16 elems; kt-invariant
  const u16* gA0 = A  + (size_t)m0 * HD;
  const u16* gB0 = Bt + (size_t)n0 * HD;
  int ldsOff0 = wid * 512;                        // u16; wave-uniform dests
  int ldsOff1 = 2048 + wid * 512;                 // +64 rows = +32 stripes

  auto stage = [&](int kt, int b) {
    const u16* pa = gA0 + voff + kt * BK;
    const u16* pb = gB0 + voff + kt * BK;
    gld_lds16(pa,                   &As[b][ldsOff0]);
    gld_lds16(pa + (size_t)64 * HD, &As[b][ldsOff1]);
    gld_lds16(pb,                   &Bs[b][ldsOff0]);
    gld_lds16(pb + (size_t)64 * HD, &Bs[b][ldsOff1]);
  };

  // ---- fragment read offsets (u16 elements) ----
  int oct = (((r & 1) << 2) + q) ^ ((r >> 1) & 7);
  int aoff[4], boff[4];
  #pragma unroll
  for (int x = 0; x < 4; ++x) {
    aoff[x] = (wm * 32 + x * 8 + (r >> 1)) * 64 + oct * 8;
    boff[x] = (wn * 32 + x * 8 + (r >> 1)) * 64 + oct * 8;
  }

  auto compute = [&](int b) {
    short8 af[4];
    #pragma unroll
    for (int x = 0; x < 4; ++x) af[x] = *(const short8*)(&As[b][aoff[x]]);
    #pragma unroll
    for (int ni = 0; ni < 4; ++ni) {
      short8 bf = *(const short8*)(&Bs[b][boff[ni]]);
      #pragma unroll
      for (int mi = 0; mi < 4; ++mi)
        acc[mi][ni] = __builtin_amdgcn_mfma_f32_16x16x32_bf16(af[mi], bf, acc[mi][ni], 0, 0, 0);
    }
  };

  // prologue: slots 0,1 in flight
  stage(0, 0);
  stage(1, 1);
  int cur = 0;                      // kt % 3
  #pragma unroll 1
  for (int kt = 0; kt < KTS; ++kt) {
    if (kt < KTS - 1) {
      __builtin_amdgcn_s_waitcnt(VMCNT_IMM(4));   // drain stage(kt) (oldest 4 ops)
    } else {
      __builtin_amdgcn_s_waitcnt(VMCNT_IMM(0));   // last: drain everything
    }
    __builtin_amdgcn_s_barrier();                 // all stages(kt) visible, slot (kt-1)%3 free
    if (kt + 2 < KTS) {
      int ns = (cur == 0) ? 2 : cur - 1;          // (cur+2)%3 == slot of kt+2
      stage(kt + 2, ns);
    }
    compute(cur);
    cur = (cur == 2) ? 0 : cur + 1;
  }

  if (EPI == 2) {
    #pragma unroll
    for (int mi = 0; mi < 4; ++mi) {
      int rowb = m0 + wm * 64 + mi * 16 + q * 4;
      #pragma unroll
      for (int ni = 0; ni < 4; ++ni) {
        int col = n0 + wn * 64 + ni * 16 + r;
        #pragma unroll
        for (int e = 0; e < 4; ++e)
          Cf[(size_t)(rowb + e) * HD + col] = acc[mi][ni][e];
      }
    }
  } else if (EPI == 0) {
    #pragma unroll
    for (int mi = 0; mi < 4; ++mi) {
      int rowb = m0 + wm * 64 + mi * 16 + q * 4;
      #pragma unroll
      for (int ni = 0; ni < 4; ++ni) {
        int col = n0 + wn * 64 + ni * 16 + r;
        float bcol = bias[col];
        #pragma unroll
        for (int e = 0; e < 4; ++e) {
          float v = acc[mi][ni][e] + bcol;
          v = v > 0.f ? v : 0.f;
          C[(size_t)(rowb + e) * HD + col] = f2bu(v);
        }
      }
    }
  } else {
    float bcol[4], s0c[4], s1c[4], s2c[4], wsc[4];
    #pragma unroll
    for (int ni = 0; ni < 4; ++ni) {
      int col = n0 + wn * 64 + ni * 16 + r;
      bcol[ni] = bias[col]; s0c[ni] = S0[col]; s1c[ni] = S1v[col];
      s2c[ni] = S2v[col];  wsc[ni] = Ws2[col];
    }
    #pragma unroll
    for (int mi = 0; mi < 4; ++mi) {
      int rowb = m0 + wm * 64 + mi * 16 + q * 4;
      #pragma unroll
      for (int e = 0; e < 4; ++e) {
        int row = rowb + e;
        float fi = (float)spI[row];
        float fe = (float)spE[row];
        float fl = fe - fi;
        float p = 0.f;
        #pragma unroll
        for (int ni = 0; ni < 4; ++ni) {
          float v = acc[mi][ni][e] + bcol[ni] + fl * s0c[ni] + fi * s1c[ni] + fe * s2c[ni];
          v = v > 0.f ? v : 0.f;
          p += v * wsc[ni];
        }
        p += __shfl_xor(p, 1);
        p += __shfl_xor(p, 2);
        p += __shfl_xor(p, 4);
        p += __shfl_xor(p, 8);
        if (r == 0 && row < SPANS) atomicAdd(&scores[row], p);
      }
    }
  }
}

extern "C" void kernel_launch(void* const* d_in, const int* in_sizes, int n_in,
                              void* d_out, int out_size, void* d_ws, size_t ws_size,
                              hipStream_t stream) {
  const int*   sent = (const int*)d_in[0];
  const int*   pos  = (const int*)d_in[1];
  const float* Wwrd = (const float*)d_in[2];
  const float* Wpos = (const float*)d_in[3];
  const float* Wd1  = (const float*)d_in[4];
  const float* bd1  = (const float*)d_in[5];
  const float* Wd2  = (const float*)d_in[6];
  const float* bd2  = (const float*)d_in[7];
  const float* Ws1  = (const float*)d_in[8];
  const float* bs1  = (const float*)d_in[9];
  const float* Ws2  = (const float*)d_in[10];
  const float* bs2  = (const float*)d_in[11];
  float* scores = (float*)d_out;

  char* w = (char*)d_ws;
  size_t o = 0;
  auto alloc = [&](size_t bytes) {
    char* p = w + o;
    o = (o + bytes + 255) & ~(size_t)255;
    return p;
  };
  int*   spI   = (int*)  alloc((size_t)MPAD * 4);
  int*   spE   = (int*)  alloc((size_t)MPAD * 4);
  float* spInv = (float*)alloc((size_t)MPAD * 4);
  float* S0    = (float*)alloc(4096);
  float* S1v   = (float*)alloc(4096);
  float* S2v   = (float*)alloc(4096);
  u16*   embB  = (u16*)  alloc((size_t)NTOK * HD * 2);
  float* Ybuf  = (float*)alloc((size_t)NTOK * HD * 4);
  float* Qp    = (float*)alloc((size_t)(NTOK + 1) * HD * 4);
  u16* Wd1t = (u16*)alloc((size_t)HD * HD * 2);
  u16* Wd2t = (u16*)alloc((size_t)HD * HD * 2);
  u16* Ws1t = (u16*)alloc((size_t)HD * HD * 2);
  u16* bufA = (u16*)alloc((size_t)MPAD * HD * 2);
  u16* bufB = (u16*)alloc((size_t)MPAD * HD * 2);

  emb_gather<<<NTOK, 256, 0, stream>>>(sent, pos, Wwrd, Wpos, embB);
  prep_spans<<<(MPAD + 255) / 256, 256, 0, stream>>>(spI, spE, spInv, scores, bs2);
  prep_castT<<<3 * 1024, 256, 0, stream>>>(Wd1, Wd2, Ws1, Wd1t, Wd2t, Ws1t);
  prep_svec <<<4, 256, 0, stream>>>(Ws1, S0, S1v, S2v);

  // Y = emb @ Wd1  (384x1024x1024, 24 blocks, fp32 out)
  gemm_bt<2><<<(NTOK / 128) * 8, 256, 0, stream>>>(embB, Wd1t, nullptr, nullptr, Ybuf,
                                                   nullptr, nullptr, nullptr, nullptr, nullptr,
                                                   nullptr, nullptr);
  yscan<<<HD, NTOK, 0, stream>>>(Ybuf, Qp);
  expand<<<MPAD / 2, 256, 0, stream>>>(Qp, spI, spE, spInv, bd1, bufA);

  gemm_bt<0><<<MTILES * 8, 256, 0, stream>>>(bufA, Wd2t, bd2, bufB, nullptr,
                                             nullptr, nullptr, nullptr, nullptr, nullptr,
                                             nullptr, nullptr);
  gemm_bt<1><<<MTILES * 8, 256, 0, stream>>>(bufB, Ws1t, bs1, nullptr, nullptr,
                                             spI, spE, S0, S1v, S2v, Ws2, scores);
}

// Round 6
// 579.194 us; speedup vs baseline: 1.5166x; 1.1156x over previous
//
#include <hip/hip_runtime.h>

#define NTOK  384
#define SPANS 73920          // 384*385/2
#define MTILES 584           // 73*8 so grid=584*8 maps cleanly onto 8 XCDs
#define MPAD  (MTILES * 128) // 74752
#define HD    1024
#define BK    32
#define KTS   (HD / BK)      // 32
#define YSLICE ((size_t)NTOK * HD)

typedef unsigned short u16;
typedef __attribute__((ext_vector_type(8))) short short8;
typedef __attribute__((ext_vector_type(4))) float floatx4;

// gfx9 s_waitcnt immediate: vmcnt[3:0]|[15:14], expcnt[6:4], lgkmcnt[11:8]
#define VMCNT_IMM(N) (((N) & 0xF) | (((N) >> 4) << 14) | (0x7 << 4) | (0xF << 8))

__device__ __forceinline__ u16 f2bu(float x) {
  union { float f; unsigned u; } un; un.f = x;
  unsigned r = un.u + 0x7fffu + ((un.u >> 16) & 1u);   // RNE
  return (u16)(r >> 16);
}

__device__ __forceinline__ void gld_lds16(const void* g, void* l) {
  __builtin_amdgcn_global_load_lds(
      (const __attribute__((address_space(1))) void*)g,
      (__attribute__((address_space(3))) void*)l, 16, 0, 0);
}

// ---- fused prep: castT (3072 blocks) | emb_gather (384) | spans (292) | svec (4) ----
__global__ void prep_misc(const int* __restrict__ sent, const int* __restrict__ pos,
                          const float* __restrict__ Wwrd, const float* __restrict__ Wpos,
                          u16* __restrict__ embB,
                          int* __restrict__ spI, int* __restrict__ spE, float* __restrict__ spInv,
                          float* __restrict__ scores, const float* __restrict__ bs2,
                          const float* __restrict__ Wd1, const float* __restrict__ Wd2,
                          const float* __restrict__ Ws1,
                          u16* __restrict__ o1, u16* __restrict__ o2, u16* __restrict__ o3,
                          float* __restrict__ S0, float* __restrict__ S1v, float* __restrict__ S2v) {
  __shared__ u16 tile[32][33];
  int bx = blockIdx.x;
  if (bx < 3072) {
    // transpose+cast the three 1024x1024 weight blocks to bf16 B^T [N][K]
    int w = bx >> 10, rem = bx & 1023;
    int tk = rem >> 5, tn = rem & 31;
    const float* src = (w == 0) ? Wd1 : ((w == 1) ? Wd2 : Ws1);
    u16* dst = (w == 0) ? o1 : ((w == 1) ? o2 : o3);
    int x = threadIdx.x & 31, y = threadIdx.x >> 5;   // y in 0..7
    int k0 = tk * 32, n0 = tn * 32;
    for (int yy = 0; yy < 32; yy += 8)
      tile[y + yy][x] = f2bu(src[(size_t)(k0 + y + yy) * HD + n0 + x]);
    __syncthreads();
    for (int yy = 0; yy < 32; yy += 8)
      dst[(size_t)(n0 + y + yy) * HD + k0 + x] = tile[x][y + yy];
  } else if (bx < 3072 + NTOK) {
    // gather token embeddings as bf16 [384][1024]
    int t = bx - 3072;
    int c = threadIdx.x;
    int pt = pos[t], st = sent[t];
    #pragma unroll
    for (int u = 0; u < 4; ++u) {
      int col = u * 256 + c;
      float v = (col < 512) ? Wpos[(size_t)pt * 512 + col]
                            : Wwrd[(size_t)st * 512 + (col - 512)];
      embB[(size_t)t * HD + col] = f2bu(v);
    }
  } else if (bx < 3072 + NTOK + 292) {
    // span (i, end, 1/len) + scores init
    int rf = (bx - 3072 - NTOK) * 256 + threadIdx.x;
    if (rf >= MPAD) return;
    int s = rf < SPANS ? rf : SPANS - 1;
    const int n = NTOK;
    double tn2 = 2.0 * n + 1.0;
    int i = (int)((tn2 - sqrt(tn2 * tn2 - 8.0 * (double)s)) * 0.5);
    if (i < 0) i = 0;
    if (i > n - 1) i = n - 1;
    #define OFF(ii) (((ii) * (2 * n - (ii) + 1)) / 2)
    while (i + 1 <= n - 1 && OFF(i + 1) <= s) ++i;
    while (i > 0 && OFF(i) > s) --i;
    int j = i + (s - OFF(i));
    #undef OFF
    spI[rf] = i;
    spE[rf] = j + 1;
    spInv[rf] = 1.0f / (float)(j + 1 - i);
    if (rf < SPANS) scores[rf] = bs2[0];
  } else {
    // S0/S1/S2 = column sums of W_s1's feat rows (len/start/end, 16 each)
    int c = (bx - 3072 - NTOK - 292) * 256 + threadIdx.x;
    if (c >= HD) return;
    float a = 0.f, b = 0.f, d = 0.f;
    for (int r = 0; r < 16; ++r) {
      a += Ws1[(size_t)(1024 + r) * HD + c];
      b += Ws1[(size_t)(1040 + r) * HD + c];
      d += Ws1[(size_t)(1056 + r) * HD + c];
    }
    S0[c] = a; S1v[c] = b; S2v[c] = d;
  }
}

// ---- Qp = [0; cumsum(sum of 4 K-partials, rows)] fp32, per-column parallel scan ----
__global__ void yscan(const float* __restrict__ Y, float* __restrict__ Qp) {
  __shared__ float buf[NTOK];
  int c = blockIdx.x;           // 0..1023
  int t = threadIdx.x;          // 0..383
  size_t idx = (size_t)t * HD + c;
  buf[t] = Y[idx] + Y[idx + YSLICE] + Y[idx + 2 * YSLICE] + Y[idx + 3 * YSLICE];
  __syncthreads();
  #pragma unroll
  for (int off = 1; off < NTOK; off <<= 1) {
    float add = (t >= off) ? buf[t - off] : 0.f;
    __syncthreads();
    buf[t] += add;
    __syncthreads();
  }
  if (t == 0) Qp[c] = 0.f;
  Qp[(size_t)(t + 1) * HD + c] = buf[t];
}

// ---- expand: h1[s] = relu((Qp[e]-Qp[i])*inv + b1) -> bf16 [MPAD][1024] ----
__global__ void expand(const float* __restrict__ Qp, const int* __restrict__ spI,
                       const int* __restrict__ spE, const float* __restrict__ spInv,
                       const float* __restrict__ b1, u16* __restrict__ out) {
  int gid = blockIdx.x * 256 + threadIdx.x;   // MPAD*128 threads
  int row = gid >> 7;
  int c0 = (gid & 127) << 3;
  int i = spI[row], e = spE[row];
  float inv = spInv[row];
  const float* pe = Qp + (size_t)e * HD + c0;
  const float* pi = Qp + (size_t)i * HD + c0;
  const float* bb = b1 + c0;
  u16 tmp[8];
  #pragma unroll
  for (int u = 0; u < 8; ++u) {
    float v = (pe[u] - pi[u]) * inv + bb[u];
    v = v > 0.f ? v : 0.f;
    tmp[u] = f2bu(v);
  }
  *(uint4*)(out + (size_t)row * HD + c0) = *(const uint4*)tmp;
}

// ---- GEMM: C[M,1024] = A[M,1024] @ B^T[1024,1024]^T (+ bias, relu)
// 128x128 tile, 4 waves of 64x64, 16x16x32 MFMA, BK=32,
// 0-conflict stripe layout (2 rows per 128-B stripe).
// Round-6 change: SINGLE barrier per K-step, ping-pong (32 KB LDS, 3 blocks/CU):
//   regs hold kt's fragments (preloaded last iter)
//   MFMA(regs)                      -- register-only
//   vmcnt(0)                        -- drains stage(kt+1), issued one full iter ago
//   s_barrier                       -- certifies: all waves' stage(kt+1) landed
//                                      AND all waves consumed regs[kt]
//   stage(kt+2, slot kt&1)          -- slot kt&1 provably free after the barrier
//   preload regs[kt+1] from slot (kt+1)&1
// EPI==0: relu+bias, store bf16 C.
// EPI==1: + feats affine, relu, dot W_s2, atomicAdd scores.
// EPI==2: plain fp32 store, split-K x4 (grid 96, each block 8 K-steps, partial ks).
template <int EPI>
__global__ __launch_bounds__(256, 3) void gemm_bt(
    const u16* __restrict__ A, const u16* __restrict__ Bt,
    const float* __restrict__ bias, u16* __restrict__ C, float* __restrict__ Cf,
    const int* __restrict__ spI, const int* __restrict__ spE,
    const float* __restrict__ S0, const float* __restrict__ S1v, const float* __restrict__ S2v,
    const float* __restrict__ Ws2, float* __restrict__ scores) {
  __shared__ u16 As[2][128 * BK];   // 8 KB per buffer; [stripe(64)][128B]
  __shared__ u16 Bs[2][128 * BK];
  int bx = blockIdx.x;
  int mt, nt, ks = 0, KT0 = 0, KT1 = KTS;
  if (EPI == 2) {
    int rem = bx & 31;
    nt = rem & 7; ks = rem >> 3; mt = bx >> 5;     // grid 96 = 3mt x 8nt x 4ks
    KT0 = ks * 8; KT1 = KT0 + 8;
  } else {
    int xcd = bx & 7, k = bx >> 3;
    nt = k & 7;
    mt = xcd + 8 * (k >> 3);        // mt%8 == xcd; blocks per XCD share mt (A L2 reuse)
  }
  int m0 = mt * 128, n0 = nt * 128;
  int t = threadIdx.x, lane = t & 63, wid = t >> 6;
  int wm = wid >> 1, wn = wid & 1;
  int q = lane >> 4, r = lane & 15;

  floatx4 acc[4][4] = {};

  // ---- staging geometry (stripe s holds rows 2s,2s+1; sub=(row&1)*4+koct at
  // octet sub^(s&7); one DMA op = 16 rows x 64B, swizzle invariant under +64 rows) ----
  int dsub = (lane & 7) ^ ((lane >> 3) & 7);
  int row0 = wid * 16 + 2 * (lane >> 3) + (dsub >> 2);
  int voff = row0 * HD + (dsub & 3) * 8;          // u16 elems; kt-invariant
  const u16* gA0 = A  + (size_t)m0 * HD;
  const u16* gB0 = Bt + (size_t)n0 * HD;
  int ldsOff0 = wid * 512;                        // u16; wave-uniform dests
  int ldsOff1 = 2048 + wid * 512;                 // +64 rows = +32 stripes

  auto stage = [&](int kt, int b) {
    const u16* pa = gA0 + voff + kt * BK;
    const u16* pb = gB0 + voff + kt * BK;
    gld_lds16(pa,                   &As[b][ldsOff0]);
    gld_lds16(pa + (size_t)64 * HD, &As[b][ldsOff1]);
    gld_lds16(pb,                   &Bs[b][ldsOff0]);
    gld_lds16(pb + (size_t)64 * HD, &Bs[b][ldsOff1]);
  };

  // ---- fragment read offsets (u16 elements) ----
  int oct = (((r & 1) << 2) + q) ^ ((r >> 1) & 7);
  int aoff[4], boff[4];
  #pragma unroll
  for (int x = 0; x < 4; ++x) {
    aoff[x] = (wm * 32 + x * 8 + (r >> 1)) * 64 + oct * 8;
    boff[x] = (wn * 32 + x * 8 + (r >> 1)) * 64 + oct * 8;
  }

  short8 af[4], bf[4];
  auto preload = [&](int b) {
    #pragma unroll
    for (int x = 0; x < 4; ++x) af[x] = *(const short8*)(&As[b][aoff[x]]);
    #pragma unroll
    for (int x = 0; x < 4; ++x) bf[x] = *(const short8*)(&Bs[b][boff[x]]);
  };
  auto mfma_burst = [&]() {
    #pragma unroll
    for (int ni = 0; ni < 4; ++ni)
      #pragma unroll
      for (int mi = 0; mi < 4; ++mi)
        acc[mi][ni] = __builtin_amdgcn_mfma_f32_16x16x32_bf16(af[mi], bf[ni], acc[mi][ni], 0, 0, 0);
  };

  // prologue: slots for KT0, KT0+1 in flight; wait KT0, preload its fragments
  stage(KT0, 0);
  stage(KT0 + 1, 1);
  __builtin_amdgcn_s_waitcnt(VMCNT_IMM(4));       // KT0's 4 ops done; KT0+1 in flight
  __builtin_amdgcn_s_barrier();
  preload(0);
  #pragma unroll 1
  for (int kt = KT0; kt < KT1; ++kt) {
    int cur = kt & 1;                             // KT0 is even (ks*8)
    mfma_burst();                                 // compiler inserts lgkm waits
    __builtin_amdgcn_s_waitcnt(VMCNT_IMM(0));     // drains stage(kt+1), 1 iter in flight
    __builtin_amdgcn_s_barrier();                 // stage(kt+1) landed (all waves); regs[kt] consumed (all waves)
    if (kt + 2 < KT1) stage(kt + 2, cur);         // slot kt&1 is free
    if (kt + 1 < KT1) preload(cur ^ 1);           // fragments for next iter
  }

  if (EPI == 2) {
    float* Cfk = Cf + (size_t)ks * YSLICE;
    #pragma unroll
    for (int mi = 0; mi < 4; ++mi) {
      int rowb = m0 + wm * 64 + mi * 16 + q * 4;
      #pragma unroll
      for (int ni = 0; ni < 4; ++ni) {
        int col = n0 + wn * 64 + ni * 16 + r;
        #pragma unroll
        for (int e = 0; e < 4; ++e)
          Cfk[(size_t)(rowb + e) * HD + col] = acc[mi][ni][e];
      }
    }
  } else if (EPI == 0) {
    #pragma unroll
    for (int mi = 0; mi < 4; ++mi) {
      int rowb = m0 + wm * 64 + mi * 16 + q * 4;
      #pragma unroll
      for (int ni = 0; ni < 4; ++ni) {
        int col = n0 + wn * 64 + ni * 16 + r;
        float bcol = bias[col];
        #pragma unroll
        for (int e = 0; e < 4; ++e) {
          float v = acc[mi][ni][e] + bcol;
          v = v > 0.f ? v : 0.f;
          C[(size_t)(rowb + e) * HD + col] = f2bu(v);
        }
      }
    }
  } else {
    float bcol[4], s0c[4], s1c[4], s2c[4], wsc[4];
    #pragma unroll
    for (int ni = 0; ni < 4; ++ni) {
      int col = n0 + wn * 64 + ni * 16 + r;
      bcol[ni] = bias[col]; s0c[ni] = S0[col]; s1c[ni] = S1v[col];
      s2c[ni] = S2v[col];  wsc[ni] = Ws2[col];
    }
    #pragma unroll
    for (int mi = 0; mi < 4; ++mi) {
      int rowb = m0 + wm * 64 + mi * 16 + q * 4;
      #pragma unroll
      for (int e = 0; e < 4; ++e) {
        int row = rowb + e;
        float fi = (float)spI[row];
        float fe = (float)spE[row];
        float fl = fe - fi;
        float p = 0.f;
        #pragma unroll
        for (int ni = 0; ni < 4; ++ni) {
          float v = acc[mi][ni][e] + bcol[ni] + fl * s0c[ni] + fi * s1c[ni] + fe * s2c[ni];
          v = v > 0.f ? v : 0.f;
          p += v * wsc[ni];
        }
        p += __shfl_xor(p, 1);
        p += __shfl_xor(p, 2);
        p += __shfl_xor(p, 4);
        p += __shfl_xor(p, 8);
        if (r == 0 && row < SPANS) atomicAdd(&scores[row], p);
      }
    }
  }
}

extern "C" void kernel_launch(void* const* d_in, const int* in_sizes, int n_in,
                              void* d_out, int out_size, void* d_ws, size_t ws_size,
                              hipStream_t stream) {
  const int*   sent = (const int*)d_in[0];
  const int*   pos  = (const int*)d_in[1];
  const float* Wwrd = (const float*)d_in[2];
  const float* Wpos = (const float*)d_in[3];
  const float* Wd1  = (const float*)d_in[4];
  const float* bd1  = (const float*)d_in[5];
  const float* Wd2  = (const float*)d_in[6];
  const float* bd2  = (const float*)d_in[7];
  const float* Ws1  = (const float*)d_in[8];
  const float* bs1  = (const float*)d_in[9];
  const float* Ws2  = (const float*)d_in[10];
  const float* bs2  = (const float*)d_in[11];
  float* scores = (float*)d_out;

  char* w = (char*)d_ws;
  size_t o = 0;
  auto alloc = [&](size_t bytes) {
    char* p = w + o;
    o = (o + bytes + 255) & ~(size_t)255;
    return p;
  };
  int*   spI   = (int*)  alloc((size_t)MPAD * 4);
  int*   spE   = (int*)  alloc((size_t)MPAD * 4);
  float* spInv = (float*)alloc((size_t)MPAD * 4);
  float* S0    = (float*)alloc(4096);
  float* S1v   = (float*)alloc(4096);
  float* S2v   = (float*)alloc(4096);
  u16*   embB  = (u16*)  alloc((size_t)NTOK * HD * 2);
  float* Ybuf  = (float*)alloc(4 * YSLICE * 4);      // 4 split-K partials
  float* Qp    = (float*)alloc((size_t)(NTOK + 1) * HD * 4);
  u16* Wd1t = (u16*)alloc((size_t)HD * HD * 2);
  u16* Wd2t = (u16*)alloc((size_t)HD * HD * 2);
  u16* Ws1t = (u16*)alloc((size_t)HD * HD * 2);
  u16* bufA = (u16*)alloc((size_t)MPAD * HD * 2);
  u16* bufB = (u16*)alloc((size_t)MPAD * HD * 2);

  // fused prep: castT | emb_gather | spans+scores-init | svec
  prep_misc<<<3072 + NTOK + 292 + 4, 256, 0, stream>>>(
      sent, pos, Wwrd, Wpos, embB,
      spI, spE, spInv, scores, bs2,
      Wd1, Wd2, Ws1, Wd1t, Wd2t, Ws1t,
      S0, S1v, S2v);

  // Y = emb @ Wd1  (384x1024x1024, split-K x4 -> 96 blocks, fp32 partials)
  gemm_bt<2><<<96, 256, 0, stream>>>(embB, Wd1t, nullptr, nullptr, Ybuf,
                                     nullptr, nullptr, nullptr, nullptr, nullptr,
                                     nullptr, nullptr);
  yscan<<<HD, NTOK, 0, stream>>>(Ybuf, Qp);
  expand<<<MPAD / 2, 256, 0, stream>>>(Qp, spI, spE, spInv, bd1, bufA);

  gemm_bt<0><<<MTILES * 8, 256, 0, stream>>>(bufA, Wd2t, bd2, bufB, nullptr,
                                             nullptr, nullptr, nullptr, nullptr, nullptr,
                                             nullptr, nullptr);
  gemm_bt<1><<<MTILES * 8, 256, 0, stream>>>(bufB, Ws1t, bs1, nullptr, nullptr,
                                             spI, spE, S0, S1v, S2v, Ws2, scores);
}